// Round 8
// baseline (222.595 us; speedup 1.0000x reference)
//
#include <hip/hip_runtime.h>
#include <hip/hip_bf16.h>

// GraphConv x3 + ReLU + log_softmax on MI355X — bf16/MFMA pipeline.
// Per layer: [T|S] = H @ [Wr|Ws] via mfma_f32_16x16x32_bf16 (K=128 one LDS
// stage, 128x128 tile/block, 4 waves x 4x4 mfma). Then atomic-free
// aggregation (bf16 gather, fp32 accum): H' = relu(sum_j T[esrc[j]] + br + S).
// Layer 3 fuses log_softmax (8-lane shuffle groups), fp32 out.
// Edge store: single-pass placement into fixed 64-slot rows.
// R7: (1) pad_kernel writes dummy idx 40000 into pad slots -> aggregate inner
//     loop is mask-free (was 8 cmp + 8 cndmask per iter); (2) float2 ext-vector
//     accumulators to coax v_pk_add_f32; (3) place processes 4 edges/thread
//     via int4. Dummy row 40000 zero-written by each mm (R5 invariant, kept).

#define N_NODES 40000
#define N_EDGES 640000
#define PAD_NODES 40064        // 313 * 128
#define DEG_CAP   40960        // int4-aligned >= N_NODES
#define ROW_CAP   64           // esrc slots per node

typedef float v4f __attribute__((ext_vector_type(4)));
typedef float v2f __attribute__((ext_vector_type(2)));
typedef short short8 __attribute__((ext_vector_type(8)));

__device__ inline unsigned short f2b(float f) {  // RNE fp32->bf16
    unsigned u = __float_as_uint(f);
    return (unsigned short)((u + 0x7fffu + ((u >> 16) & 1u)) >> 16);
}

// ---------------------------------------------------------------- prep
// deg zero + W transpose+cast to bf16.
__global__ __launch_bounds__(256) void prep_kernel(const float* __restrict__ Wr0, const float* __restrict__ Ws0,
                                                   const float* __restrict__ Wr1, const float* __restrict__ Ws1,
                                                   const float* __restrict__ Wr2, const float* __restrict__ Ws2,
                                                   unsigned short* __restrict__ Wt0,
                                                   unsigned short* __restrict__ Wt1,
                                                   unsigned short* __restrict__ Wt2,
                                                   int* __restrict__ deg) {
    int tid = blockIdx.x * 256 + threadIdx.x;
    if (tid < DEG_CAP / 4) {
        ((int4*)deg)[tid] = make_int4(0, 0, 0, 0);
    } else {
        int t = tid - DEG_CAP / 4;
        if (t < 32768) {
            int n = t >> 7, k = t & 127;
            const float* W = (n < 128) ? Wr0 : Ws0;
            Wt0[t] = f2b(W[k * 128 + (n & 127)]);
        } else if (t < 65536) {
            int u = t - 32768;
            int n = u >> 7, k = u & 127;
            const float* W = (n < 128) ? Wr1 : Ws1;
            Wt1[u] = f2b(W[k * 128 + (n & 127)]);
        } else if (t < 81920) {
            int u = t - 65536;
            int n = u >> 7, k = u & 127;
            const float* W = (n < 64) ? Wr2 : Ws2;
            Wt2[u] = f2b(W[k * 64 + (n & 63)]);
        }
    }
}

// ---------------------------------------------------------------- edge placement
// 4 edges per thread: slot = atomicAdd(deg[dst]); esrc[dst*64+slot] = src.
__global__ __launch_bounds__(256) void place_kernel(const int* __restrict__ src,
                                                    const int* __restrict__ dst,
                                                    int* __restrict__ deg,
                                                    int* __restrict__ esrc) {
    int e4 = blockIdx.x * 256 + threadIdx.x;   // grid 625 -> 160000 threads
    int4 s = ((const int4*)src)[e4];
    int4 d = ((const int4*)dst)[e4];
    int r;
    r = atomicAdd(&deg[d.x], 1); if (r < ROW_CAP) esrc[(size_t)d.x * ROW_CAP + r] = s.x;
    r = atomicAdd(&deg[d.y], 1); if (r < ROW_CAP) esrc[(size_t)d.y * ROW_CAP + r] = s.y;
    r = atomicAdd(&deg[d.z], 1); if (r < ROW_CAP) esrc[(size_t)d.z * ROW_CAP + r] = s.z;
    r = atomicAdd(&deg[d.w], 1); if (r < ROW_CAP) esrc[(size_t)d.w * ROW_CAP + r] = s.w;
}

// ---------------------------------------------------------------- pad fill
// Fill slots [deg[n], roundup8(deg[n])) with dummy node 40000 so the aggregate
// inner loop needs no masking. <=7 scattered stores per node.
__global__ __launch_bounds__(256) void pad_kernel(const int* __restrict__ deg,
                                                  int* __restrict__ esrc) {
    int n = blockIdx.x * 256 + threadIdx.x;
    if (n < N_NODES) {
        int c = deg[n]; if (c > ROW_CAP) c = ROW_CAP;
        int pc = (c + 7) & ~7;
        for (int r = c; r < pc; r++) esrc[(size_t)n * ROW_CAP + r] = N_NODES;
    }
}

// ---------------------------------------------------------------- MFMA matmul
// A: [PAD_NODES][128] (bf16, or fp32 when F32 — converted during staging).
// Wt: [2*DO][128] bf16 pre-transposed. Block 256 thr = 4 waves, tile 128x128.
// Stores zeros at node == N_NODES (the aggregate's dummy/pad row).
template <int DO, bool F32>
__global__ __launch_bounds__(256) void mm_kernel(const void* __restrict__ Ain,
                                                 const unsigned short* __restrict__ Wt,
                                                 unsigned short* __restrict__ T,
                                                 unsigned short* __restrict__ S) {
    __shared__ unsigned short As[128 * 128];  // 32 KB
    __shared__ unsigned short Bs[128 * 128];  // 32 KB

    const int tid = threadIdx.x;
    const int m0  = blockIdx.x * 128;
    const int n0  = blockIdx.y * 128;

    if (F32) {
        const float4* Xg = (const float4*)Ain;
#pragma unroll
        for (int i = 0; i < 16; i++) {
            int idx = i * 256 + tid;          // float4 index in tile
            int row = idx >> 5, c4 = idx & 31;
            int gr = m0 + row;
            if (gr > N_NODES - 1) gr = N_NODES - 1;  // pad tile: clamp (OOB-safe)
            float4 v = Xg[(size_t)gr * 32 + c4];
            uint2 p;
            p.x = (unsigned)f2b(v.x) | ((unsigned)f2b(v.y) << 16);
            p.y = (unsigned)f2b(v.z) | ((unsigned)f2b(v.w) << 16);
            ((uint2*)As)[idx] = p;
        }
    } else {
        const uint4* ga = (const uint4*)((const unsigned short*)Ain + (size_t)m0 * 128);
#pragma unroll
        for (int i = 0; i < 8; i++) ((uint4*)As)[i * 256 + tid] = ga[i * 256 + tid];
    }
    {
        const uint4* gb = (const uint4*)(Wt + (size_t)n0 * 128);
#pragma unroll
        for (int i = 0; i < 8; i++) ((uint4*)Bs)[i * 256 + tid] = gb[i * 256 + tid];
    }
    __syncthreads();

    const int wave = tid >> 6;
    const int lane = tid & 63;
    const int wr   = (wave >> 1) * 64;
    const int wc   = (wave & 1) * 64;
    const int qm   = lane & 15;
    const int k8   = (lane >> 4) * 8;

    v4f acc[4][4];
#pragma unroll
    for (int i = 0; i < 4; i++)
#pragma unroll
        for (int j = 0; j < 4; j++) acc[i][j] = (v4f)(0.0f);

#pragma unroll
    for (int ks = 0; ks < 4; ks++) {
        short8 af[4], bf[4];
#pragma unroll
        for (int i = 0; i < 4; i++) {
            af[i] = *(const short8*)(const void*)(As + (wr + i * 16 + qm) * 128 + ks * 32 + k8);
            bf[i] = *(const short8*)(const void*)(Bs + (wc + i * 16 + qm) * 128 + ks * 32 + k8);
        }
#pragma unroll
        for (int mi = 0; mi < 4; mi++)
#pragma unroll
            for (int ni = 0; ni < 4; ni++)
                acc[mi][ni] = __builtin_amdgcn_mfma_f32_16x16x32_bf16(af[mi], bf[ni], acc[mi][ni], 0, 0, 0);
    }

    // C/D layout: col=lane&15, row=(lane>>4)*4+reg  [m89-verified]
    // node == N_NODES -> write ZEROS (dummy row read by aggregate pad slots).
#pragma unroll
    for (int mi = 0; mi < 4; mi++) {
        const int nodeBase = m0 + wr + mi * 16 + ((lane >> 4) << 2);
#pragma unroll
        for (int r = 0; r < 4; r++) {
            const int node = nodeBase + r;
            if (node <= N_NODES) {
                const bool real = (node < N_NODES);
#pragma unroll
                for (int ni = 0; ni < 4; ni++) {
                    const int c = wc + ni * 16 + qm;
                    const unsigned short hv = real ? f2b(acc[mi][ni][r]) : (unsigned short)0;
                    if (DO == 128) {
                        (blockIdx.y ? S : T)[(size_t)node * 128 + c] = hv;
                    } else {
                        if (c < 64) T[(size_t)node * 64 + c] = hv;
                        else        S[(size_t)node * 64 + (c - 64)] = hv;
                    }
                }
            }
        }
    }
}

// ---------------------------------------------------------------- aggregate
// H[n] = relu(sum_j T[esrc[n*64+j]] + br + S[n]); bf16 in, fp32 accum.
// TPN = DO/8 threads/node, 8 dims each. Pad slots pre-filled with dummy node
// 40000 (zero row) -> mask-free 8-wide inner loop. float2 acc for pk_add_f32.
__device__ inline void addp(v2f* a, uint4 q) {
    v2f t0 = { __uint_as_float(q.x << 16), __uint_as_float(q.x & 0xffff0000u) };
    v2f t1 = { __uint_as_float(q.y << 16), __uint_as_float(q.y & 0xffff0000u) };
    v2f t2 = { __uint_as_float(q.z << 16), __uint_as_float(q.z & 0xffff0000u) };
    v2f t3 = { __uint_as_float(q.w << 16), __uint_as_float(q.w & 0xffff0000u) };
    a[0] += t0; a[1] += t1; a[2] += t2; a[3] += t3;
}

template <int DO, bool LAST>
__global__ __launch_bounds__(256) void aggregate_kernel(const unsigned short* __restrict__ T,
                                                        const unsigned short* __restrict__ S,
                                                        const float* __restrict__ br,
                                                        const int* __restrict__ deg,
                                                        const int* __restrict__ esrc,
                                                        unsigned short* __restrict__ Hout,
                                                        float* __restrict__ Fout) {
    constexpr int TPN = DO / 8;        // 16 (DO=128) or 8 (DO=64)
    constexpr int G   = 256 / TPN;     // nodes per block
    const int lane = threadIdx.x % TPN;
    const int n    = blockIdx.x * G + threadIdx.x / TPN;

    int cnt = deg[n];
    if (cnt > ROW_CAP) cnt = ROW_CAP;  // safety (never expected)
    const int pcnt = (cnt + 7) & ~7;
    const int* erow = esrc + (size_t)n * ROW_CAP;
    const uint4* T4 = (const uint4*)T;

    const uint4  sv = ((const uint4*)S)[(size_t)n * TPN + lane];
    const float4 b0 = ((const float4*)br)[lane * 2];
    const float4 b1 = ((const float4*)br)[lane * 2 + 1];

    v2f acc[4];
    acc[0] = (v2f)(0.0f); acc[1] = (v2f)(0.0f);
    acc[2] = (v2f)(0.0f); acc[3] = (v2f)(0.0f);

    for (int o = 0; o < pcnt; o += 8) {
        int4 i0 = *(const int4*)(erow + o);
        int4 i1 = *(const int4*)(erow + o + 4);
        uint4 q0 = T4[(size_t)i0.x * TPN + lane];
        uint4 q1 = T4[(size_t)i0.y * TPN + lane];
        uint4 q2 = T4[(size_t)i0.z * TPN + lane];
        uint4 q3 = T4[(size_t)i0.w * TPN + lane];
        uint4 q4 = T4[(size_t)i1.x * TPN + lane];
        uint4 q5 = T4[(size_t)i1.y * TPN + lane];
        uint4 q6 = T4[(size_t)i1.z * TPN + lane];
        uint4 q7 = T4[(size_t)i1.w * TPN + lane];
        addp(acc, q0); addp(acc, q1); addp(acc, q2); addp(acc, q3);
        addp(acc, q4); addp(acc, q5); addp(acc, q6); addp(acc, q7);
    }
    addp(acc, sv);  // root term

    float v[8];
    v[0] = fmaxf(acc[0].x + b0.x, 0.f); v[1] = fmaxf(acc[0].y + b0.y, 0.f);
    v[2] = fmaxf(acc[1].x + b0.z, 0.f); v[3] = fmaxf(acc[1].y + b0.w, 0.f);
    v[4] = fmaxf(acc[2].x + b1.x, 0.f); v[5] = fmaxf(acc[2].y + b1.y, 0.f);
    v[6] = fmaxf(acc[3].x + b1.z, 0.f); v[7] = fmaxf(acc[3].y + b1.w, 0.f);

    if (LAST) {
        // DO=64, TPN=8: 8-lane shuffle groups; log_softmax
        float m = v[0];
#pragma unroll
        for (int i = 1; i < 8; i++) m = fmaxf(m, v[i]);
#pragma unroll
        for (int off = 4; off; off >>= 1) m = fmaxf(m, __shfl_xor(m, off, 64));
        float es = 0.f;
#pragma unroll
        for (int i = 0; i < 8; i++) es += expf(v[i] - m);
#pragma unroll
        for (int off = 4; off; off >>= 1) es += __shfl_xor(es, off, 64);
        float lse = m + logf(es);
        float4 o0 = make_float4(v[0] - lse, v[1] - lse, v[2] - lse, v[3] - lse);
        float4 o1 = make_float4(v[4] - lse, v[5] - lse, v[6] - lse, v[7] - lse);
        ((float4*)Fout)[(size_t)n * 16 + lane * 2]     = o0;
        ((float4*)Fout)[(size_t)n * 16 + lane * 2 + 1] = o1;
    } else {
        uint4 o;
        o.x = (unsigned)f2b(v[0]) | ((unsigned)f2b(v[1]) << 16);
        o.y = (unsigned)f2b(v[2]) | ((unsigned)f2b(v[3]) << 16);
        o.z = (unsigned)f2b(v[4]) | ((unsigned)f2b(v[5]) << 16);
        o.w = (unsigned)f2b(v[6]) | ((unsigned)f2b(v[7]) << 16);
        ((uint4*)Hout)[(size_t)n * TPN + lane] = o;
    }
}

// ---------------------------------------------------------------- launch

extern "C" void kernel_launch(void* const* d_in, const int* in_sizes, int n_in,
                              void* d_out, int out_size, void* d_ws, size_t ws_size,
                              hipStream_t stream) {
    const float* x    = (const float*)d_in[0];
    const int*   eidx = (const int*)d_in[1];   // [2, E] int32
    const float* Wr0  = (const float*)d_in[2];
    const float* br0  = (const float*)d_in[3];
    const float* Ws0  = (const float*)d_in[4];
    const float* Wr1  = (const float*)d_in[5];
    const float* br1  = (const float*)d_in[6];
    const float* Ws1  = (const float*)d_in[7];
    const float* Wr2  = (const float*)d_in[8];
    const float* br2  = (const float*)d_in[9];
    const float* Ws2  = (const float*)d_in[10];
    float* out = (float*)d_out;

    const int* src = eidx;
    const int* dst = eidx + N_EDGES;

    auto align = [](size_t v) { return (v + 255) & ~(size_t)255; };
    char* w = (char*)d_ws;
    int* deg  = (int*)w;  w += align(sizeof(int) * DEG_CAP);
    int* esrc = (int*)w;  w += align(sizeof(int) * (size_t)N_NODES * ROW_CAP);
    unsigned short* H1b = (unsigned short*)w;  w += align(2ull * PAD_NODES * 128);
    unsigned short* H2b = (unsigned short*)w;  w += align(2ull * PAD_NODES * 128);
    unsigned short* Wt0 = (unsigned short*)w;  w += align(2ull * 256 * 128);
    unsigned short* Wt1 = (unsigned short*)w;  w += align(2ull * 256 * 128);
    unsigned short* Wt2 = (unsigned short*)w;  w += align(2ull * 128 * 128);
    unsigned short* T   = (unsigned short*)w;  w += align(2ull * PAD_NODES * 128);
    unsigned short* Sb  = (unsigned short*)w;  w += align(2ull * PAD_NODES * 128);
    (void)ws_size; (void)n_in; (void)in_sizes; (void)out_size;

    // ---- prep: deg zero + W casts
    prep_kernel<<<(DEG_CAP / 4 + 81920 + 255) / 256, 256, 0, stream>>>(
        Wr0, Ws0, Wr1, Ws1, Wr2, Ws2, Wt0, Wt1, Wt2, deg);

    // ---- edge placement (single pass, 4 edges/thread) + pad fill
    place_kernel<<<N_EDGES / 4 / 256, 256, 0, stream>>>(src, dst, deg, esrc);
    pad_kernel<<<(N_NODES + 255) / 256, 256, 0, stream>>>(deg, esrc);

    // ---- layer 1 (fp32 X read directly)
    mm_kernel<128, true><<<dim3(PAD_NODES / 128, 2), 256, 0, stream>>>(x, Wt0, T, Sb);
    aggregate_kernel<128, false><<<N_NODES / 16, 256, 0, stream>>>(T, Sb, br0, deg, esrc, H1b, nullptr);

    // ---- layer 2
    mm_kernel<128, false><<<dim3(PAD_NODES / 128, 2), 256, 0, stream>>>(H1b, Wt1, T, Sb);
    aggregate_kernel<128, false><<<N_NODES / 16, 256, 0, stream>>>(T, Sb, br1, deg, esrc, H2b, nullptr);

    // ---- layer 3 (fused log_softmax, fp32 out)
    mm_kernel<64, false><<<dim3(PAD_NODES / 128, 1), 256, 0, stream>>>(H2b, Wt2, T, Sb);
    aggregate_kernel<64, true><<<N_NODES / 32, 256, 0, stream>>>(T, Sb, br2, deg, esrc, nullptr, out);
}

// Round 9
// 219.039 us; speedup vs baseline: 1.0162x; 1.0162x over previous
//
#include <hip/hip_runtime.h>
#include <hip/hip_bf16.h>

// GraphConv x3 + ReLU + log_softmax on MI355X — bf16/MFMA pipeline.
// Per layer: [T|S] = H @ [Wr|Ws] via mfma_f32_16x16x32_bf16 (K=128 one LDS
// stage, 128x128 tile/block, 4 waves x 4x4 mfma). Then atomic-free
// aggregation (bf16 gather, fp32 accum): H' = relu(sum_j T[esrc[j]] + br + S).
// Layer 3 fuses log_softmax (8-lane shuffle groups), fp32 out.
// Edge store: single-pass placement into fixed 64-slot rows; pad slots filled
// with dummy node 40000 -> mask-free 8-wide aggregate loop; dummy row zeroed
// by each mm (R5 invariant).
// R8: REVERT place to 1 edge/thread. R7's 4-edge/thread cut waves 4x
//     (occupancy 21.6%, VALUBusy 0.29%) -> 46us latency-bound regression;
//     scattered 4B stores dirty full 64B lines (WRITE_SIZE 39MB for 2.5MB
//     logical) so place needs maximal TLP, not fewer waves.

#define N_NODES 40000
#define N_EDGES 640000
#define PAD_NODES 40064        // 313 * 128
#define DEG_CAP   40960        // int4-aligned >= N_NODES
#define ROW_CAP   64           // esrc slots per node

typedef float v4f __attribute__((ext_vector_type(4)));
typedef float v2f __attribute__((ext_vector_type(2)));
typedef short short8 __attribute__((ext_vector_type(8)));

__device__ inline unsigned short f2b(float f) {  // RNE fp32->bf16
    unsigned u = __float_as_uint(f);
    return (unsigned short)((u + 0x7fffu + ((u >> 16) & 1u)) >> 16);
}

// ---------------------------------------------------------------- prep
// deg zero + W transpose+cast to bf16.
__global__ __launch_bounds__(256) void prep_kernel(const float* __restrict__ Wr0, const float* __restrict__ Ws0,
                                                   const float* __restrict__ Wr1, const float* __restrict__ Ws1,
                                                   const float* __restrict__ Wr2, const float* __restrict__ Ws2,
                                                   unsigned short* __restrict__ Wt0,
                                                   unsigned short* __restrict__ Wt1,
                                                   unsigned short* __restrict__ Wt2,
                                                   int* __restrict__ deg) {
    int tid = blockIdx.x * 256 + threadIdx.x;
    if (tid < DEG_CAP / 4) {
        ((int4*)deg)[tid] = make_int4(0, 0, 0, 0);
    } else {
        int t = tid - DEG_CAP / 4;
        if (t < 32768) {
            int n = t >> 7, k = t & 127;
            const float* W = (n < 128) ? Wr0 : Ws0;
            Wt0[t] = f2b(W[k * 128 + (n & 127)]);
        } else if (t < 65536) {
            int u = t - 32768;
            int n = u >> 7, k = u & 127;
            const float* W = (n < 128) ? Wr1 : Ws1;
            Wt1[u] = f2b(W[k * 128 + (n & 127)]);
        } else if (t < 81920) {
            int u = t - 65536;
            int n = u >> 7, k = u & 127;
            const float* W = (n < 64) ? Wr2 : Ws2;
            Wt2[u] = f2b(W[k * 64 + (n & 63)]);
        }
    }
}

// ---------------------------------------------------------------- edge placement
// 1 edge/thread (max TLP to hide atomic+scatter latency):
// slot = atomicAdd(deg[dst]); esrc[dst*64+slot] = src.
__global__ __launch_bounds__(256) void place_kernel(const int* __restrict__ src,
                                                    const int* __restrict__ dst,
                                                    int* __restrict__ deg,
                                                    int* __restrict__ esrc) {
    int e = blockIdx.x * 256 + threadIdx.x;
    if (e < N_EDGES) {
        int d = dst[e];
        int r = atomicAdd(&deg[d], 1);
        if (r < ROW_CAP) esrc[(size_t)d * ROW_CAP + r] = src[e];
    }
}

// ---------------------------------------------------------------- pad fill
// Fill slots [deg[n], roundup8(deg[n])) with dummy node 40000 so the aggregate
// inner loop needs no masking. <=7 scattered stores per node.
__global__ __launch_bounds__(256) void pad_kernel(const int* __restrict__ deg,
                                                  int* __restrict__ esrc) {
    int n = blockIdx.x * 256 + threadIdx.x;
    if (n < N_NODES) {
        int c = deg[n]; if (c > ROW_CAP) c = ROW_CAP;
        int pc = (c + 7) & ~7;
        for (int r = c; r < pc; r++) esrc[(size_t)n * ROW_CAP + r] = N_NODES;
    }
}

// ---------------------------------------------------------------- MFMA matmul
// A: [PAD_NODES][128] (bf16, or fp32 when F32 — converted during staging).
// Wt: [2*DO][128] bf16 pre-transposed. Block 256 thr = 4 waves, tile 128x128.
// Stores zeros at node == N_NODES (the aggregate's dummy/pad row).
template <int DO, bool F32>
__global__ __launch_bounds__(256) void mm_kernel(const void* __restrict__ Ain,
                                                 const unsigned short* __restrict__ Wt,
                                                 unsigned short* __restrict__ T,
                                                 unsigned short* __restrict__ S) {
    __shared__ unsigned short As[128 * 128];  // 32 KB
    __shared__ unsigned short Bs[128 * 128];  // 32 KB

    const int tid = threadIdx.x;
    const int m0  = blockIdx.x * 128;
    const int n0  = blockIdx.y * 128;

    if (F32) {
        const float4* Xg = (const float4*)Ain;
#pragma unroll
        for (int i = 0; i < 16; i++) {
            int idx = i * 256 + tid;          // float4 index in tile
            int row = idx >> 5, c4 = idx & 31;
            int gr = m0 + row;
            if (gr > N_NODES - 1) gr = N_NODES - 1;  // pad tile: clamp (OOB-safe)
            float4 v = Xg[(size_t)gr * 32 + c4];
            uint2 p;
            p.x = (unsigned)f2b(v.x) | ((unsigned)f2b(v.y) << 16);
            p.y = (unsigned)f2b(v.z) | ((unsigned)f2b(v.w) << 16);
            ((uint2*)As)[idx] = p;
        }
    } else {
        const uint4* ga = (const uint4*)((const unsigned short*)Ain + (size_t)m0 * 128);
#pragma unroll
        for (int i = 0; i < 8; i++) ((uint4*)As)[i * 256 + tid] = ga[i * 256 + tid];
    }
    {
        const uint4* gb = (const uint4*)(Wt + (size_t)n0 * 128);
#pragma unroll
        for (int i = 0; i < 8; i++) ((uint4*)Bs)[i * 256 + tid] = gb[i * 256 + tid];
    }
    __syncthreads();

    const int wave = tid >> 6;
    const int lane = tid & 63;
    const int wr   = (wave >> 1) * 64;
    const int wc   = (wave & 1) * 64;
    const int qm   = lane & 15;
    const int k8   = (lane >> 4) * 8;

    v4f acc[4][4];
#pragma unroll
    for (int i = 0; i < 4; i++)
#pragma unroll
        for (int j = 0; j < 4; j++) acc[i][j] = (v4f)(0.0f);

#pragma unroll
    for (int ks = 0; ks < 4; ks++) {
        short8 af[4], bf[4];
#pragma unroll
        for (int i = 0; i < 4; i++) {
            af[i] = *(const short8*)(const void*)(As + (wr + i * 16 + qm) * 128 + ks * 32 + k8);
            bf[i] = *(const short8*)(const void*)(Bs + (wc + i * 16 + qm) * 128 + ks * 32 + k8);
        }
#pragma unroll
        for (int mi = 0; mi < 4; mi++)
#pragma unroll
            for (int ni = 0; ni < 4; ni++)
                acc[mi][ni] = __builtin_amdgcn_mfma_f32_16x16x32_bf16(af[mi], bf[ni], acc[mi][ni], 0, 0, 0);
    }

    // C/D layout: col=lane&15, row=(lane>>4)*4+reg  [m89-verified]
    // node == N_NODES -> write ZEROS (dummy row read by aggregate pad slots).
#pragma unroll
    for (int mi = 0; mi < 4; mi++) {
        const int nodeBase = m0 + wr + mi * 16 + ((lane >> 4) << 2);
#pragma unroll
        for (int r = 0; r < 4; r++) {
            const int node = nodeBase + r;
            if (node <= N_NODES) {
                const bool real = (node < N_NODES);
#pragma unroll
                for (int ni = 0; ni < 4; ni++) {
                    const int c = wc + ni * 16 + qm;
                    const unsigned short hv = real ? f2b(acc[mi][ni][r]) : (unsigned short)0;
                    if (DO == 128) {
                        (blockIdx.y ? S : T)[(size_t)node * 128 + c] = hv;
                    } else {
                        if (c < 64) T[(size_t)node * 64 + c] = hv;
                        else        S[(size_t)node * 64 + (c - 64)] = hv;
                    }
                }
            }
        }
    }
}

// ---------------------------------------------------------------- aggregate
// H[n] = relu(sum_j T[esrc[n*64+j]] + br + S[n]); bf16 in, fp32 accum.
// TPN = DO/8 threads/node, 8 dims each. Pad slots pre-filled with dummy node
// 40000 (zero row) -> mask-free 8-wide inner loop. float2 acc for pk_add_f32.
__device__ inline void addp(v2f* a, uint4 q) {
    v2f t0 = { __uint_as_float(q.x << 16), __uint_as_float(q.x & 0xffff0000u) };
    v2f t1 = { __uint_as_float(q.y << 16), __uint_as_float(q.y & 0xffff0000u) };
    v2f t2 = { __uint_as_float(q.z << 16), __uint_as_float(q.z & 0xffff0000u) };
    v2f t3 = { __uint_as_float(q.w << 16), __uint_as_float(q.w & 0xffff0000u) };
    a[0] += t0; a[1] += t1; a[2] += t2; a[3] += t3;
}

template <int DO, bool LAST>
__global__ __launch_bounds__(256) void aggregate_kernel(const unsigned short* __restrict__ T,
                                                        const unsigned short* __restrict__ S,
                                                        const float* __restrict__ br,
                                                        const int* __restrict__ deg,
                                                        const int* __restrict__ esrc,
                                                        unsigned short* __restrict__ Hout,
                                                        float* __restrict__ Fout) {
    constexpr int TPN = DO / 8;        // 16 (DO=128) or 8 (DO=64)
    constexpr int G   = 256 / TPN;     // nodes per block
    const int lane = threadIdx.x % TPN;
    const int n    = blockIdx.x * G + threadIdx.x / TPN;

    int cnt = deg[n];
    if (cnt > ROW_CAP) cnt = ROW_CAP;  // safety (never expected)
    const int pcnt = (cnt + 7) & ~7;
    const int* erow = esrc + (size_t)n * ROW_CAP;
    const uint4* T4 = (const uint4*)T;

    const uint4  sv = ((const uint4*)S)[(size_t)n * TPN + lane];
    const float4 b0 = ((const float4*)br)[lane * 2];
    const float4 b1 = ((const float4*)br)[lane * 2 + 1];

    v2f acc[4];
    acc[0] = (v2f)(0.0f); acc[1] = (v2f)(0.0f);
    acc[2] = (v2f)(0.0f); acc[3] = (v2f)(0.0f);

    for (int o = 0; o < pcnt; o += 8) {
        int4 i0 = *(const int4*)(erow + o);
        int4 i1 = *(const int4*)(erow + o + 4);
        uint4 q0 = T4[(size_t)i0.x * TPN + lane];
        uint4 q1 = T4[(size_t)i0.y * TPN + lane];
        uint4 q2 = T4[(size_t)i0.z * TPN + lane];
        uint4 q3 = T4[(size_t)i0.w * TPN + lane];
        uint4 q4 = T4[(size_t)i1.x * TPN + lane];
        uint4 q5 = T4[(size_t)i1.y * TPN + lane];
        uint4 q6 = T4[(size_t)i1.z * TPN + lane];
        uint4 q7 = T4[(size_t)i1.w * TPN + lane];
        addp(acc, q0); addp(acc, q1); addp(acc, q2); addp(acc, q3);
        addp(acc, q4); addp(acc, q5); addp(acc, q6); addp(acc, q7);
    }
    addp(acc, sv);  // root term

    float v[8];
    v[0] = fmaxf(acc[0].x + b0.x, 0.f); v[1] = fmaxf(acc[0].y + b0.y, 0.f);
    v[2] = fmaxf(acc[1].x + b0.z, 0.f); v[3] = fmaxf(acc[1].y + b0.w, 0.f);
    v[4] = fmaxf(acc[2].x + b1.x, 0.f); v[5] = fmaxf(acc[2].y + b1.y, 0.f);
    v[6] = fmaxf(acc[3].x + b1.z, 0.f); v[7] = fmaxf(acc[3].y + b1.w, 0.f);

    if (LAST) {
        // DO=64, TPN=8: 8-lane shuffle groups; log_softmax
        float m = v[0];
#pragma unroll
        for (int i = 1; i < 8; i++) m = fmaxf(m, v[i]);
#pragma unroll
        for (int off = 4; off; off >>= 1) m = fmaxf(m, __shfl_xor(m, off, 64));
        float es = 0.f;
#pragma unroll
        for (int i = 0; i < 8; i++) es += expf(v[i] - m);
#pragma unroll
        for (int off = 4; off; off >>= 1) es += __shfl_xor(es, off, 64);
        float lse = m + logf(es);
        float4 o0 = make_float4(v[0] - lse, v[1] - lse, v[2] - lse, v[3] - lse);
        float4 o1 = make_float4(v[4] - lse, v[5] - lse, v[6] - lse, v[7] - lse);
        ((float4*)Fout)[(size_t)n * 16 + lane * 2]     = o0;
        ((float4*)Fout)[(size_t)n * 16 + lane * 2 + 1] = o1;
    } else {
        uint4 o;
        o.x = (unsigned)f2b(v[0]) | ((unsigned)f2b(v[1]) << 16);
        o.y = (unsigned)f2b(v[2]) | ((unsigned)f2b(v[3]) << 16);
        o.z = (unsigned)f2b(v[4]) | ((unsigned)f2b(v[5]) << 16);
        o.w = (unsigned)f2b(v[6]) | ((unsigned)f2b(v[7]) << 16);
        ((uint4*)Hout)[(size_t)n * TPN + lane] = o;
    }
}

// ---------------------------------------------------------------- launch

extern "C" void kernel_launch(void* const* d_in, const int* in_sizes, int n_in,
                              void* d_out, int out_size, void* d_ws, size_t ws_size,
                              hipStream_t stream) {
    const float* x    = (const float*)d_in[0];
    const int*   eidx = (const int*)d_in[1];   // [2, E] int32
    const float* Wr0  = (const float*)d_in[2];
    const float* br0  = (const float*)d_in[3];
    const float* Ws0  = (const float*)d_in[4];
    const float* Wr1  = (const float*)d_in[5];
    const float* br1  = (const float*)d_in[6];
    const float* Ws1  = (const float*)d_in[7];
    const float* Wr2  = (const float*)d_in[8];
    const float* br2  = (const float*)d_in[9];
    const float* Ws2  = (const float*)d_in[10];
    float* out = (float*)d_out;

    const int* src = eidx;
    const int* dst = eidx + N_EDGES;

    auto align = [](size_t v) { return (v + 255) & ~(size_t)255; };
    char* w = (char*)d_ws;
    int* deg  = (int*)w;  w += align(sizeof(int) * DEG_CAP);
    int* esrc = (int*)w;  w += align(sizeof(int) * (size_t)N_NODES * ROW_CAP);
    unsigned short* H1b = (unsigned short*)w;  w += align(2ull * PAD_NODES * 128);
    unsigned short* H2b = (unsigned short*)w;  w += align(2ull * PAD_NODES * 128);
    unsigned short* Wt0 = (unsigned short*)w;  w += align(2ull * 256 * 128);
    unsigned short* Wt1 = (unsigned short*)w;  w += align(2ull * 256 * 128);
    unsigned short* Wt2 = (unsigned short*)w;  w += align(2ull * 128 * 128);
    unsigned short* T   = (unsigned short*)w;  w += align(2ull * PAD_NODES * 128);
    unsigned short* Sb  = (unsigned short*)w;  w += align(2ull * PAD_NODES * 128);
    (void)ws_size; (void)n_in; (void)in_sizes; (void)out_size;

    // ---- prep: deg zero + W casts
    prep_kernel<<<(DEG_CAP / 4 + 81920 + 255) / 256, 256, 0, stream>>>(
        Wr0, Ws0, Wr1, Ws1, Wr2, Ws2, Wt0, Wt1, Wt2, deg);

    // ---- edge placement (1 edge/thread, max TLP) + pad fill
    place_kernel<<<(N_EDGES + 255) / 256, 256, 0, stream>>>(src, dst, deg, esrc);
    pad_kernel<<<(N_NODES + 255) / 256, 256, 0, stream>>>(deg, esrc);

    // ---- layer 1 (fp32 X read directly)
    mm_kernel<128, true><<<dim3(PAD_NODES / 128, 2), 256, 0, stream>>>(x, Wt0, T, Sb);
    aggregate_kernel<128, false><<<N_NODES / 16, 256, 0, stream>>>(T, Sb, br0, deg, esrc, H1b, nullptr);

    // ---- layer 2
    mm_kernel<128, false><<<dim3(PAD_NODES / 128, 2), 256, 0, stream>>>(H1b, Wt1, T, Sb);
    aggregate_kernel<128, false><<<N_NODES / 16, 256, 0, stream>>>(T, Sb, br1, deg, esrc, H2b, nullptr);

    // ---- layer 3 (fused log_softmax, fp32 out)
    mm_kernel<64, false><<<dim3(PAD_NODES / 128, 1), 256, 0, stream>>>(H2b, Wt2, T, Sb);
    aggregate_kernel<64, true><<<N_NODES / 32, 256, 0, stream>>>(T, Sb, br2, deg, esrc, nullptr, out);
}

// Round 10
// 216.878 us; speedup vs baseline: 1.0264x; 1.0100x over previous
//
#include <hip/hip_runtime.h>
#include <hip/hip_bf16.h>

// GraphConv x3 + ReLU + log_softmax on MI355X — bf16/MFMA pipeline.
// Per layer: [T|S] = H @ [Wr|Ws] via mfma_f32_16x16x32_bf16 (K=128 one LDS
// stage, 128x128 tile/block, 4 waves x 4x4 mfma). Then atomic-free
// aggregation (bf16 gather, fp32 accum): H' = relu(sum_j T[esrc[j]] + br + S).
// Layer 3 fuses log_softmax (8-lane shuffle groups), fp32 out.
// Edge store: single-pass placement into fixed 64-slot rows (1 edge/thread,
// max TLP — R8 lesson). Aggregate masks pad slots IN-REGISTER (R6 style).
// R9: drop pad_kernel (R7's mask-free loop saved ~0.3us of VALU but cost a
//     dispatch + scattered stores ~4us — optimized a non-bottleneck). Keep
//     v2f packed accumulators. 8 dispatches. Dummy row 40000 zero-written by
//     each mm (R5 invariant) for masked pad reads.

#define N_NODES 40000
#define N_EDGES 640000
#define PAD_NODES 40064        // 313 * 128
#define DEG_CAP   40960        // int4-aligned >= N_NODES
#define ROW_CAP   64           // esrc slots per node

typedef float v4f __attribute__((ext_vector_type(4)));
typedef float v2f __attribute__((ext_vector_type(2)));
typedef short short8 __attribute__((ext_vector_type(8)));

__device__ inline unsigned short f2b(float f) {  // RNE fp32->bf16
    unsigned u = __float_as_uint(f);
    return (unsigned short)((u + 0x7fffu + ((u >> 16) & 1u)) >> 16);
}

// ---------------------------------------------------------------- prep
// deg zero + W transpose+cast to bf16.
__global__ __launch_bounds__(256) void prep_kernel(const float* __restrict__ Wr0, const float* __restrict__ Ws0,
                                                   const float* __restrict__ Wr1, const float* __restrict__ Ws1,
                                                   const float* __restrict__ Wr2, const float* __restrict__ Ws2,
                                                   unsigned short* __restrict__ Wt0,
                                                   unsigned short* __restrict__ Wt1,
                                                   unsigned short* __restrict__ Wt2,
                                                   int* __restrict__ deg) {
    int tid = blockIdx.x * 256 + threadIdx.x;
    if (tid < DEG_CAP / 4) {
        ((int4*)deg)[tid] = make_int4(0, 0, 0, 0);
    } else {
        int t = tid - DEG_CAP / 4;
        if (t < 32768) {
            int n = t >> 7, k = t & 127;
            const float* W = (n < 128) ? Wr0 : Ws0;
            Wt0[t] = f2b(W[k * 128 + (n & 127)]);
        } else if (t < 65536) {
            int u = t - 32768;
            int n = u >> 7, k = u & 127;
            const float* W = (n < 128) ? Wr1 : Ws1;
            Wt1[u] = f2b(W[k * 128 + (n & 127)]);
        } else if (t < 81920) {
            int u = t - 65536;
            int n = u >> 7, k = u & 127;
            const float* W = (n < 64) ? Wr2 : Ws2;
            Wt2[u] = f2b(W[k * 64 + (n & 63)]);
        }
    }
}

// ---------------------------------------------------------------- edge placement
// 1 edge/thread (max TLP to hide atomic+scatter latency):
// slot = atomicAdd(deg[dst]); esrc[dst*64+slot] = src.
__global__ __launch_bounds__(256) void place_kernel(const int* __restrict__ src,
                                                    const int* __restrict__ dst,
                                                    int* __restrict__ deg,
                                                    int* __restrict__ esrc) {
    int e = blockIdx.x * 256 + threadIdx.x;
    if (e < N_EDGES) {
        int d = dst[e];
        int r = atomicAdd(&deg[d], 1);
        if (r < ROW_CAP) esrc[(size_t)d * ROW_CAP + r] = src[e];
    }
}

// ---------------------------------------------------------------- MFMA matmul
// A: [PAD_NODES][128] (bf16, or fp32 when F32 — converted during staging).
// Wt: [2*DO][128] bf16 pre-transposed. Block 256 thr = 4 waves, tile 128x128.
// Stores zeros at node == N_NODES (the aggregate's dummy/pad row).
template <int DO, bool F32>
__global__ __launch_bounds__(256) void mm_kernel(const void* __restrict__ Ain,
                                                 const unsigned short* __restrict__ Wt,
                                                 unsigned short* __restrict__ T,
                                                 unsigned short* __restrict__ S) {
    __shared__ unsigned short As[128 * 128];  // 32 KB
    __shared__ unsigned short Bs[128 * 128];  // 32 KB

    const int tid = threadIdx.x;
    const int m0  = blockIdx.x * 128;
    const int n0  = blockIdx.y * 128;

    if (F32) {
        const float4* Xg = (const float4*)Ain;
#pragma unroll
        for (int i = 0; i < 16; i++) {
            int idx = i * 256 + tid;          // float4 index in tile
            int row = idx >> 5, c4 = idx & 31;
            int gr = m0 + row;
            if (gr > N_NODES - 1) gr = N_NODES - 1;  // pad tile: clamp (OOB-safe)
            float4 v = Xg[(size_t)gr * 32 + c4];
            uint2 p;
            p.x = (unsigned)f2b(v.x) | ((unsigned)f2b(v.y) << 16);
            p.y = (unsigned)f2b(v.z) | ((unsigned)f2b(v.w) << 16);
            ((uint2*)As)[idx] = p;
        }
    } else {
        const uint4* ga = (const uint4*)((const unsigned short*)Ain + (size_t)m0 * 128);
#pragma unroll
        for (int i = 0; i < 8; i++) ((uint4*)As)[i * 256 + tid] = ga[i * 256 + tid];
    }
    {
        const uint4* gb = (const uint4*)(Wt + (size_t)n0 * 128);
#pragma unroll
        for (int i = 0; i < 8; i++) ((uint4*)Bs)[i * 256 + tid] = gb[i * 256 + tid];
    }
    __syncthreads();

    const int wave = tid >> 6;
    const int lane = tid & 63;
    const int wr   = (wave >> 1) * 64;
    const int wc   = (wave & 1) * 64;
    const int qm   = lane & 15;
    const int k8   = (lane >> 4) * 8;

    v4f acc[4][4];
#pragma unroll
    for (int i = 0; i < 4; i++)
#pragma unroll
        for (int j = 0; j < 4; j++) acc[i][j] = (v4f)(0.0f);

#pragma unroll
    for (int ks = 0; ks < 4; ks++) {
        short8 af[4], bf[4];
#pragma unroll
        for (int i = 0; i < 4; i++) {
            af[i] = *(const short8*)(const void*)(As + (wr + i * 16 + qm) * 128 + ks * 32 + k8);
            bf[i] = *(const short8*)(const void*)(Bs + (wc + i * 16 + qm) * 128 + ks * 32 + k8);
        }
#pragma unroll
        for (int mi = 0; mi < 4; mi++)
#pragma unroll
            for (int ni = 0; ni < 4; ni++)
                acc[mi][ni] = __builtin_amdgcn_mfma_f32_16x16x32_bf16(af[mi], bf[ni], acc[mi][ni], 0, 0, 0);
    }

    // C/D layout: col=lane&15, row=(lane>>4)*4+reg  [m89-verified]
    // node == N_NODES -> write ZEROS (dummy row read by aggregate pad slots).
#pragma unroll
    for (int mi = 0; mi < 4; mi++) {
        const int nodeBase = m0 + wr + mi * 16 + ((lane >> 4) << 2);
#pragma unroll
        for (int r = 0; r < 4; r++) {
            const int node = nodeBase + r;
            if (node <= N_NODES) {
                const bool real = (node < N_NODES);
#pragma unroll
                for (int ni = 0; ni < 4; ni++) {
                    const int c = wc + ni * 16 + qm;
                    const unsigned short hv = real ? f2b(acc[mi][ni][r]) : (unsigned short)0;
                    if (DO == 128) {
                        (blockIdx.y ? S : T)[(size_t)node * 128 + c] = hv;
                    } else {
                        if (c < 64) T[(size_t)node * 64 + c] = hv;
                        else        S[(size_t)node * 64 + (c - 64)] = hv;
                    }
                }
            }
        }
    }
}

// ---------------------------------------------------------------- aggregate
// H[n] = relu(sum_j T[esrc[n*64+j]] + br + S[n]); bf16 in, fp32 accum.
// TPN = DO/8 threads/node, 8 dims each. 8-wide unrolled; pad slots masked
// in-register to dummy node 40000 (zero row). v2f acc for v_pk_add_f32.
__device__ inline void addp(v2f* a, uint4 q) {
    v2f t0 = { __uint_as_float(q.x << 16), __uint_as_float(q.x & 0xffff0000u) };
    v2f t1 = { __uint_as_float(q.y << 16), __uint_as_float(q.y & 0xffff0000u) };
    v2f t2 = { __uint_as_float(q.z << 16), __uint_as_float(q.z & 0xffff0000u) };
    v2f t3 = { __uint_as_float(q.w << 16), __uint_as_float(q.w & 0xffff0000u) };
    a[0] += t0; a[1] += t1; a[2] += t2; a[3] += t3;
}

template <int DO, bool LAST>
__global__ __launch_bounds__(256) void aggregate_kernel(const unsigned short* __restrict__ T,
                                                        const unsigned short* __restrict__ S,
                                                        const float* __restrict__ br,
                                                        const int* __restrict__ deg,
                                                        const int* __restrict__ esrc,
                                                        unsigned short* __restrict__ Hout,
                                                        float* __restrict__ Fout) {
    constexpr int TPN = DO / 8;        // 16 (DO=128) or 8 (DO=64)
    constexpr int G   = 256 / TPN;     // nodes per block
    const int lane = threadIdx.x % TPN;
    const int n    = blockIdx.x * G + threadIdx.x / TPN;

    int cnt = deg[n];
    if (cnt > ROW_CAP) cnt = ROW_CAP;  // safety (never expected)
    const int* erow = esrc + (size_t)n * ROW_CAP;
    const uint4* T4 = (const uint4*)T;

    const uint4  sv = ((const uint4*)S)[(size_t)n * TPN + lane];
    const float4 b0 = ((const float4*)br)[lane * 2];
    const float4 b1 = ((const float4*)br)[lane * 2 + 1];

    v2f acc[4];
    acc[0] = (v2f)(0.0f); acc[1] = (v2f)(0.0f);
    acc[2] = (v2f)(0.0f); acc[3] = (v2f)(0.0f);

    for (int o = 0; o < cnt; o += 8) {
        int4 i0 = *(const int4*)(erow + o);
        int4 i1 = *(const int4*)(erow + o + 4);
        // mask pad slots (uninitialized) -> dummy zero row (safe addressing)
        i0.x = (o + 0 < cnt) ? i0.x : N_NODES;
        i0.y = (o + 1 < cnt) ? i0.y : N_NODES;
        i0.z = (o + 2 < cnt) ? i0.z : N_NODES;
        i0.w = (o + 3 < cnt) ? i0.w : N_NODES;
        i1.x = (o + 4 < cnt) ? i1.x : N_NODES;
        i1.y = (o + 5 < cnt) ? i1.y : N_NODES;
        i1.z = (o + 6 < cnt) ? i1.z : N_NODES;
        i1.w = (o + 7 < cnt) ? i1.w : N_NODES;
        uint4 q0 = T4[(size_t)i0.x * TPN + lane];
        uint4 q1 = T4[(size_t)i0.y * TPN + lane];
        uint4 q2 = T4[(size_t)i0.z * TPN + lane];
        uint4 q3 = T4[(size_t)i0.w * TPN + lane];
        uint4 q4 = T4[(size_t)i1.x * TPN + lane];
        uint4 q5 = T4[(size_t)i1.y * TPN + lane];
        uint4 q6 = T4[(size_t)i1.z * TPN + lane];
        uint4 q7 = T4[(size_t)i1.w * TPN + lane];
        addp(acc, q0); addp(acc, q1); addp(acc, q2); addp(acc, q3);
        addp(acc, q4); addp(acc, q5); addp(acc, q6); addp(acc, q7);
    }
    addp(acc, sv);  // root term

    float v[8];
    v[0] = fmaxf(acc[0].x + b0.x, 0.f); v[1] = fmaxf(acc[0].y + b0.y, 0.f);
    v[2] = fmaxf(acc[1].x + b0.z, 0.f); v[3] = fmaxf(acc[1].y + b0.w, 0.f);
    v[4] = fmaxf(acc[2].x + b1.x, 0.f); v[5] = fmaxf(acc[2].y + b1.y, 0.f);
    v[6] = fmaxf(acc[3].x + b1.z, 0.f); v[7] = fmaxf(acc[3].y + b1.w, 0.f);

    if (LAST) {
        // DO=64, TPN=8: 8-lane shuffle groups; log_softmax
        float m = v[0];
#pragma unroll
        for (int i = 1; i < 8; i++) m = fmaxf(m, v[i]);
#pragma unroll
        for (int off = 4; off; off >>= 1) m = fmaxf(m, __shfl_xor(m, off, 64));
        float es = 0.f;
#pragma unroll
        for (int i = 0; i < 8; i++) es += expf(v[i] - m);
#pragma unroll
        for (int off = 4; off; off >>= 1) es += __shfl_xor(es, off, 64);
        float lse = m + logf(es);
        float4 o0 = make_float4(v[0] - lse, v[1] - lse, v[2] - lse, v[3] - lse);
        float4 o1 = make_float4(v[4] - lse, v[5] - lse, v[6] - lse, v[7] - lse);
        ((float4*)Fout)[(size_t)n * 16 + lane * 2]     = o0;
        ((float4*)Fout)[(size_t)n * 16 + lane * 2 + 1] = o1;
    } else {
        uint4 o;
        o.x = (unsigned)f2b(v[0]) | ((unsigned)f2b(v[1]) << 16);
        o.y = (unsigned)f2b(v[2]) | ((unsigned)f2b(v[3]) << 16);
        o.z = (unsigned)f2b(v[4]) | ((unsigned)f2b(v[5]) << 16);
        o.w = (unsigned)f2b(v[6]) | ((unsigned)f2b(v[7]) << 16);
        ((uint4*)Hout)[(size_t)n * TPN + lane] = o;
    }
}

// ---------------------------------------------------------------- launch

extern "C" void kernel_launch(void* const* d_in, const int* in_sizes, int n_in,
                              void* d_out, int out_size, void* d_ws, size_t ws_size,
                              hipStream_t stream) {
    const float* x    = (const float*)d_in[0];
    const int*   eidx = (const int*)d_in[1];   // [2, E] int32
    const float* Wr0  = (const float*)d_in[2];
    const float* br0  = (const float*)d_in[3];
    const float* Ws0  = (const float*)d_in[4];
    const float* Wr1  = (const float*)d_in[5];
    const float* br1  = (const float*)d_in[6];
    const float* Ws1  = (const float*)d_in[7];
    const float* Wr2  = (const float*)d_in[8];
    const float* br2  = (const float*)d_in[9];
    const float* Ws2  = (const float*)d_in[10];
    float* out = (float*)d_out;

    const int* src = eidx;
    const int* dst = eidx + N_EDGES;

    auto align = [](size_t v) { return (v + 255) & ~(size_t)255; };
    char* w = (char*)d_ws;
    int* deg  = (int*)w;  w += align(sizeof(int) * DEG_CAP);
    int* esrc = (int*)w;  w += align(sizeof(int) * (size_t)N_NODES * ROW_CAP);
    unsigned short* H1b = (unsigned short*)w;  w += align(2ull * PAD_NODES * 128);
    unsigned short* H2b = (unsigned short*)w;  w += align(2ull * PAD_NODES * 128);
    unsigned short* Wt0 = (unsigned short*)w;  w += align(2ull * 256 * 128);
    unsigned short* Wt1 = (unsigned short*)w;  w += align(2ull * 256 * 128);
    unsigned short* Wt2 = (unsigned short*)w;  w += align(2ull * 128 * 128);
    unsigned short* T   = (unsigned short*)w;  w += align(2ull * PAD_NODES * 128);
    unsigned short* Sb  = (unsigned short*)w;  w += align(2ull * PAD_NODES * 128);
    (void)ws_size; (void)n_in; (void)in_sizes; (void)out_size;

    // ---- prep: deg zero + W casts
    prep_kernel<<<(DEG_CAP / 4 + 81920 + 255) / 256, 256, 0, stream>>>(
        Wr0, Ws0, Wr1, Ws1, Wr2, Ws2, Wt0, Wt1, Wt2, deg);

    // ---- edge placement (1 edge/thread, max TLP)
    place_kernel<<<(N_EDGES + 255) / 256, 256, 0, stream>>>(src, dst, deg, esrc);

    // ---- layer 1 (fp32 X read directly)
    mm_kernel<128, true><<<dim3(PAD_NODES / 128, 2), 256, 0, stream>>>(x, Wt0, T, Sb);
    aggregate_kernel<128, false><<<N_NODES / 16, 256, 0, stream>>>(T, Sb, br0, deg, esrc, H1b, nullptr);

    // ---- layer 2
    mm_kernel<128, false><<<dim3(PAD_NODES / 128, 2), 256, 0, stream>>>(H1b, Wt1, T, Sb);
    aggregate_kernel<128, false><<<N_NODES / 16, 256, 0, stream>>>(T, Sb, br1, deg, esrc, H2b, nullptr);

    // ---- layer 3 (fused log_softmax, fp32 out)
    mm_kernel<64, false><<<dim3(PAD_NODES / 128, 1), 256, 0, stream>>>(H2b, Wt2, T, Sb);
    aggregate_kernel<64, true><<<N_NODES / 32, 256, 0, stream>>>(T, Sb, br2, deg, esrc, nullptr, out);
}

// Round 11
// 208.655 us; speedup vs baseline: 1.0668x; 1.0394x over previous
//
#include <hip/hip_runtime.h>
#include <hip/hip_bf16.h>

// GraphConv x3 + ReLU + log_softmax on MI355X — bf16/MFMA pipeline.
// Per layer: [T|S] = H @ [Wr|Ws] via mfma_f32_16x16x32_bf16, then atomic-free
// aggregation (bf16 gather, fp32 accum): H' = relu(sum_j T[esrc[j]] + br + S).
// Layer 3 fuses log_softmax (8-lane shuffle groups), fp32 out.
// Edge store: single-pass placement into fixed 64-slot rows (1 edge/thread,
// max TLP — R8 lesson). Aggregate masks pad slots IN-REGISTER (R6 style);
// dummy row 40000 zero-written by each mm (R5 invariant).
// R10: K-SPLIT mm staging — K=128 staged as 2x64 halves (LDS 64->32 KB,
//      As/Bs 16 KB each). With __launch_bounds__(256,3): 3 blocks/CU ->
//      768-block co-residency >= 626-block grid, killing the mm block-tail
//      (was 2 blocks/CU, 512 capacity -> second partial wave with idle CUs).

#define N_NODES 40000
#define N_EDGES 640000
#define PAD_NODES 40064        // 313 * 128
#define DEG_CAP   40960        // int4-aligned >= N_NODES
#define ROW_CAP   64           // esrc slots per node

typedef float v4f __attribute__((ext_vector_type(4)));
typedef float v2f __attribute__((ext_vector_type(2)));
typedef short short8 __attribute__((ext_vector_type(8)));

__device__ inline unsigned short f2b(float f) {  // RNE fp32->bf16
    unsigned u = __float_as_uint(f);
    return (unsigned short)((u + 0x7fffu + ((u >> 16) & 1u)) >> 16);
}

// ---------------------------------------------------------------- prep
// deg zero + W transpose+cast to bf16.
__global__ __launch_bounds__(256) void prep_kernel(const float* __restrict__ Wr0, const float* __restrict__ Ws0,
                                                   const float* __restrict__ Wr1, const float* __restrict__ Ws1,
                                                   const float* __restrict__ Wr2, const float* __restrict__ Ws2,
                                                   unsigned short* __restrict__ Wt0,
                                                   unsigned short* __restrict__ Wt1,
                                                   unsigned short* __restrict__ Wt2,
                                                   int* __restrict__ deg) {
    int tid = blockIdx.x * 256 + threadIdx.x;
    if (tid < DEG_CAP / 4) {
        ((int4*)deg)[tid] = make_int4(0, 0, 0, 0);
    } else {
        int t = tid - DEG_CAP / 4;
        if (t < 32768) {
            int n = t >> 7, k = t & 127;
            const float* W = (n < 128) ? Wr0 : Ws0;
            Wt0[t] = f2b(W[k * 128 + (n & 127)]);
        } else if (t < 65536) {
            int u = t - 32768;
            int n = u >> 7, k = u & 127;
            const float* W = (n < 128) ? Wr1 : Ws1;
            Wt1[u] = f2b(W[k * 128 + (n & 127)]);
        } else if (t < 81920) {
            int u = t - 65536;
            int n = u >> 7, k = u & 127;
            const float* W = (n < 64) ? Wr2 : Ws2;
            Wt2[u] = f2b(W[k * 64 + (n & 63)]);
        }
    }
}

// ---------------------------------------------------------------- edge placement
// 1 edge/thread (max TLP to hide atomic+scatter latency):
// slot = atomicAdd(deg[dst]); esrc[dst*64+slot] = src.
__global__ __launch_bounds__(256) void place_kernel(const int* __restrict__ src,
                                                    const int* __restrict__ dst,
                                                    int* __restrict__ deg,
                                                    int* __restrict__ esrc) {
    int e = blockIdx.x * 256 + threadIdx.x;
    if (e < N_EDGES) {
        int d = dst[e];
        int r = atomicAdd(&deg[d], 1);
        if (r < ROW_CAP) esrc[(size_t)d * ROW_CAP + r] = src[e];
    }
}

// ---------------------------------------------------------------- MFMA matmul
// A: [PAD_NODES][128] (bf16, or fp32 when F32 — converted during staging).
// Wt: [2*DO][128] bf16 pre-transposed. Block 256 thr = 4 waves, tile 128x128.
// K staged in 2 halves of 64 (As/Bs 16 KB each). 3 blocks/CU co-residency.
// Stores zeros at node == N_NODES (the aggregate's dummy/pad row).
template <int DO, bool F32>
__global__ __launch_bounds__(256, 3) void mm_kernel(const void* __restrict__ Ain,
                                                    const unsigned short* __restrict__ Wt,
                                                    unsigned short* __restrict__ T,
                                                    unsigned short* __restrict__ S) {
    __shared__ unsigned short As[128 * 64];  // 16 KB (K-half)
    __shared__ unsigned short Bs[128 * 64];  // 16 KB

    const int tid = threadIdx.x;
    const int m0  = blockIdx.x * 128;
    const int n0  = blockIdx.y * 128;

    const int wave = tid >> 6;
    const int lane = tid & 63;
    const int wr   = (wave >> 1) * 64;
    const int wc   = (wave & 1) * 64;
    const int qm   = lane & 15;
    const int k8   = (lane >> 4) * 8;

    v4f acc[4][4];
#pragma unroll
    for (int i = 0; i < 4; i++)
#pragma unroll
        for (int j = 0; j < 4; j++) acc[i][j] = (v4f)(0.0f);

#pragma unroll
    for (int half = 0; half < 2; half++) {
        // ---- stage A half: 128 rows x 64 k
        if (F32) {
            const float4* Xg = (const float4*)Ain;   // row pitch = 32 float4
#pragma unroll
            for (int i = 0; i < 8; i++) {
                int idx = i * 256 + tid;             // 0..2047 (float4 slots)
                int row = idx >> 4, c4 = idx & 15;   // 16 float4 per row-half
                int gr = m0 + row;
                if (gr > N_NODES - 1) gr = N_NODES - 1;  // pad tile: clamp
                float4 v = Xg[(size_t)gr * 32 + half * 16 + c4];
                uint2 p;
                p.x = (unsigned)f2b(v.x) | ((unsigned)f2b(v.y) << 16);
                p.y = (unsigned)f2b(v.z) | ((unsigned)f2b(v.w) << 16);
                ((uint2*)As)[idx] = p;
            }
        } else {
            const unsigned short* Ab = (const unsigned short*)Ain;
#pragma unroll
            for (int i = 0; i < 4; i++) {
                int idx = i * 256 + tid;             // 0..1023 (uint4 slots)
                int row = idx >> 3, c8 = idx & 7;    // 8 uint4 per row-half
                ((uint4*)As)[idx] =
                    *(const uint4*)(Ab + (size_t)(m0 + row) * 128 + half * 64 + c8 * 8);
            }
        }
        // ---- stage B half: Wt rows n0..n0+127, k-half
        {
#pragma unroll
            for (int i = 0; i < 4; i++) {
                int idx = i * 256 + tid;
                int row = idx >> 3, c8 = idx & 7;
                ((uint4*)Bs)[idx] =
                    *(const uint4*)(Wt + (size_t)(n0 + row) * 128 + half * 64 + c8 * 8);
            }
        }
        __syncthreads();

#pragma unroll
        for (int ks = 0; ks < 2; ks++) {
            short8 af[4], bf[4];
#pragma unroll
            for (int i = 0; i < 4; i++) {
                af[i] = *(const short8*)(const void*)(As + (wr + i * 16 + qm) * 64 + ks * 32 + k8);
                bf[i] = *(const short8*)(const void*)(Bs + (wc + i * 16 + qm) * 64 + ks * 32 + k8);
            }
#pragma unroll
            for (int mi = 0; mi < 4; mi++)
#pragma unroll
                for (int ni = 0; ni < 4; ni++)
                    acc[mi][ni] = __builtin_amdgcn_mfma_f32_16x16x32_bf16(af[mi], bf[ni], acc[mi][ni], 0, 0, 0);
        }
        __syncthreads();
    }

    // C/D layout: col=lane&15, row=(lane>>4)*4+reg  [m89-verified]
    // node == N_NODES -> write ZEROS (dummy row read by aggregate pad slots).
#pragma unroll
    for (int mi = 0; mi < 4; mi++) {
        const int nodeBase = m0 + wr + mi * 16 + ((lane >> 4) << 2);
#pragma unroll
        for (int r = 0; r < 4; r++) {
            const int node = nodeBase + r;
            if (node <= N_NODES) {
                const bool real = (node < N_NODES);
#pragma unroll
                for (int ni = 0; ni < 4; ni++) {
                    const int c = wc + ni * 16 + qm;
                    const unsigned short hv = real ? f2b(acc[mi][ni][r]) : (unsigned short)0;
                    if (DO == 128) {
                        (blockIdx.y ? S : T)[(size_t)node * 128 + c] = hv;
                    } else {
                        if (c < 64) T[(size_t)node * 64 + c] = hv;
                        else        S[(size_t)node * 64 + (c - 64)] = hv;
                    }
                }
            }
        }
    }
}

// ---------------------------------------------------------------- aggregate
// H[n] = relu(sum_j T[esrc[n*64+j]] + br + S[n]); bf16 in, fp32 accum.
// TPN = DO/8 threads/node, 8 dims each. 8-wide unrolled; pad slots masked
// in-register to dummy node 40000 (zero row). v2f acc for v_pk_add_f32.
__device__ inline void addp(v2f* a, uint4 q) {
    v2f t0 = { __uint_as_float(q.x << 16), __uint_as_float(q.x & 0xffff0000u) };
    v2f t1 = { __uint_as_float(q.y << 16), __uint_as_float(q.y & 0xffff0000u) };
    v2f t2 = { __uint_as_float(q.z << 16), __uint_as_float(q.z & 0xffff0000u) };
    v2f t3 = { __uint_as_float(q.w << 16), __uint_as_float(q.w & 0xffff0000u) };
    a[0] += t0; a[1] += t1; a[2] += t2; a[3] += t3;
}

template <int DO, bool LAST>
__global__ __launch_bounds__(256) void aggregate_kernel(const unsigned short* __restrict__ T,
                                                        const unsigned short* __restrict__ S,
                                                        const float* __restrict__ br,
                                                        const int* __restrict__ deg,
                                                        const int* __restrict__ esrc,
                                                        unsigned short* __restrict__ Hout,
                                                        float* __restrict__ Fout) {
    constexpr int TPN = DO / 8;        // 16 (DO=128) or 8 (DO=64)
    constexpr int G   = 256 / TPN;     // nodes per block
    const int lane = threadIdx.x % TPN;
    const int n    = blockIdx.x * G + threadIdx.x / TPN;

    int cnt = deg[n];
    if (cnt > ROW_CAP) cnt = ROW_CAP;  // safety (never expected)
    const int* erow = esrc + (size_t)n * ROW_CAP;
    const uint4* T4 = (const uint4*)T;

    const uint4  sv = ((const uint4*)S)[(size_t)n * TPN + lane];
    const float4 b0 = ((const float4*)br)[lane * 2];
    const float4 b1 = ((const float4*)br)[lane * 2 + 1];

    v2f acc[4];
    acc[0] = (v2f)(0.0f); acc[1] = (v2f)(0.0f);
    acc[2] = (v2f)(0.0f); acc[3] = (v2f)(0.0f);

    for (int o = 0; o < cnt; o += 8) {
        int4 i0 = *(const int4*)(erow + o);
        int4 i1 = *(const int4*)(erow + o + 4);
        // mask pad slots (uninitialized) -> dummy zero row (safe addressing)
        i0.x = (o + 0 < cnt) ? i0.x : N_NODES;
        i0.y = (o + 1 < cnt) ? i0.y : N_NODES;
        i0.z = (o + 2 < cnt) ? i0.z : N_NODES;
        i0.w = (o + 3 < cnt) ? i0.w : N_NODES;
        i1.x = (o + 4 < cnt) ? i1.x : N_NODES;
        i1.y = (o + 5 < cnt) ? i1.y : N_NODES;
        i1.z = (o + 6 < cnt) ? i1.z : N_NODES;
        i1.w = (o + 7 < cnt) ? i1.w : N_NODES;
        uint4 q0 = T4[(size_t)i0.x * TPN + lane];
        uint4 q1 = T4[(size_t)i0.y * TPN + lane];
        uint4 q2 = T4[(size_t)i0.z * TPN + lane];
        uint4 q3 = T4[(size_t)i0.w * TPN + lane];
        uint4 q4 = T4[(size_t)i1.x * TPN + lane];
        uint4 q5 = T4[(size_t)i1.y * TPN + lane];
        uint4 q6 = T4[(size_t)i1.z * TPN + lane];
        uint4 q7 = T4[(size_t)i1.w * TPN + lane];
        addp(acc, q0); addp(acc, q1); addp(acc, q2); addp(acc, q3);
        addp(acc, q4); addp(acc, q5); addp(acc, q6); addp(acc, q7);
    }
    addp(acc, sv);  // root term

    float v[8];
    v[0] = fmaxf(acc[0].x + b0.x, 0.f); v[1] = fmaxf(acc[0].y + b0.y, 0.f);
    v[2] = fmaxf(acc[1].x + b0.z, 0.f); v[3] = fmaxf(acc[1].y + b0.w, 0.f);
    v[4] = fmaxf(acc[2].x + b1.x, 0.f); v[5] = fmaxf(acc[2].y + b1.y, 0.f);
    v[6] = fmaxf(acc[3].x + b1.z, 0.f); v[7] = fmaxf(acc[3].y + b1.w, 0.f);

    if (LAST) {
        // DO=64, TPN=8: 8-lane shuffle groups; log_softmax
        float m = v[0];
#pragma unroll
        for (int i = 1; i < 8; i++) m = fmaxf(m, v[i]);
#pragma unroll
        for (int off = 4; off; off >>= 1) m = fmaxf(m, __shfl_xor(m, off, 64));
        float es = 0.f;
#pragma unroll
        for (int i = 0; i < 8; i++) es += expf(v[i] - m);
#pragma unroll
        for (int off = 4; off; off >>= 1) es += __shfl_xor(es, off, 64);
        float lse = m + logf(es);
        float4 o0 = make_float4(v[0] - lse, v[1] - lse, v[2] - lse, v[3] - lse);
        float4 o1 = make_float4(v[4] - lse, v[5] - lse, v[6] - lse, v[7] - lse);
        ((float4*)Fout)[(size_t)n * 16 + lane * 2]     = o0;
        ((float4*)Fout)[(size_t)n * 16 + lane * 2 + 1] = o1;
    } else {
        uint4 o;
        o.x = (unsigned)f2b(v[0]) | ((unsigned)f2b(v[1]) << 16);
        o.y = (unsigned)f2b(v[2]) | ((unsigned)f2b(v[3]) << 16);
        o.z = (unsigned)f2b(v[4]) | ((unsigned)f2b(v[5]) << 16);
        o.w = (unsigned)f2b(v[6]) | ((unsigned)f2b(v[7]) << 16);
        ((uint4*)Hout)[(size_t)n * TPN + lane] = o;
    }
}

// ---------------------------------------------------------------- launch

extern "C" void kernel_launch(void* const* d_in, const int* in_sizes, int n_in,
                              void* d_out, int out_size, void* d_ws, size_t ws_size,
                              hipStream_t stream) {
    const float* x    = (const float*)d_in[0];
    const int*   eidx = (const int*)d_in[1];   // [2, E] int32
    const float* Wr0  = (const float*)d_in[2];
    const float* br0  = (const float*)d_in[3];
    const float* Ws0  = (const float*)d_in[4];
    const float* Wr1  = (const float*)d_in[5];
    const float* br1  = (const float*)d_in[6];
    const float* Ws1  = (const float*)d_in[7];
    const float* Wr2  = (const float*)d_in[8];
    const float* br2  = (const float*)d_in[9];
    const float* Ws2  = (const float*)d_in[10];
    float* out = (float*)d_out;

    const int* src = eidx;
    const int* dst = eidx + N_EDGES;

    auto align = [](size_t v) { return (v + 255) & ~(size_t)255; };
    char* w = (char*)d_ws;
    int* deg  = (int*)w;  w += align(sizeof(int) * DEG_CAP);
    int* esrc = (int*)w;  w += align(sizeof(int) * (size_t)N_NODES * ROW_CAP);
    unsigned short* H1b = (unsigned short*)w;  w += align(2ull * PAD_NODES * 128);
    unsigned short* H2b = (unsigned short*)w;  w += align(2ull * PAD_NODES * 128);
    unsigned short* Wt0 = (unsigned short*)w;  w += align(2ull * 256 * 128);
    unsigned short* Wt1 = (unsigned short*)w;  w += align(2ull * 256 * 128);
    unsigned short* Wt2 = (unsigned short*)w;  w += align(2ull * 128 * 128);
    unsigned short* T   = (unsigned short*)w;  w += align(2ull * PAD_NODES * 128);
    unsigned short* Sb  = (unsigned short*)w;  w += align(2ull * PAD_NODES * 128);
    (void)ws_size; (void)n_in; (void)in_sizes; (void)out_size;

    // ---- prep: deg zero + W casts
    prep_kernel<<<(DEG_CAP / 4 + 81920 + 255) / 256, 256, 0, stream>>>(
        Wr0, Ws0, Wr1, Ws1, Wr2, Ws2, Wt0, Wt1, Wt2, deg);

    // ---- edge placement (1 edge/thread, max TLP)
    place_kernel<<<(N_EDGES + 255) / 256, 256, 0, stream>>>(src, dst, deg, esrc);

    // ---- layer 1 (fp32 X read directly)
    mm_kernel<128, true><<<dim3(PAD_NODES / 128, 2), 256, 0, stream>>>(x, Wt0, T, Sb);
    aggregate_kernel<128, false><<<N_NODES / 16, 256, 0, stream>>>(T, Sb, br0, deg, esrc, H1b, nullptr);

    // ---- layer 2
    mm_kernel<128, false><<<dim3(PAD_NODES / 128, 2), 256, 0, stream>>>(H1b, Wt1, T, Sb);
    aggregate_kernel<128, false><<<N_NODES / 16, 256, 0, stream>>>(T, Sb, br1, deg, esrc, H2b, nullptr);

    // ---- layer 3 (fused log_softmax, fp32 out)
    mm_kernel<64, false><<<dim3(PAD_NODES / 128, 1), 256, 0, stream>>>(H2b, Wt2, T, Sb);
    aggregate_kernel<64, true><<<N_NODES / 32, 256, 0, stream>>>(T, Sb, br2, deg, esrc, nullptr, out);
}